// Round 1
// baseline (2260.910 us; speedup 1.0000x reference)
//
#include <hip/hip_runtime.h>

#define N_TOT 100000
#define IN_F  500
#define H_F   256
#define M_ROWS 50000
#define K_CL  40
#define OUT2  1024
#define BN_EPS 1e-5f

// ---------------------------------------------------------------------------
// Generic tiled fp32 GEMM:  C[r, c] = sum_k A[ar(r), k] * B[c*ldb + boff + k]
//                                     (+ bias[c]) (+ addvec[addidx[r]*OUT2+c])
// A row-major [Mrows, lda] (optionally gathered via rowidx), B row-major
// weights [Ncols, ldb] with column offset boff (to address Wfc[:, :256] vs
// Wfc[:, 256:]). 64x64 tile, 256 threads, 4x4 micro-tile, BK=16.
// LDS pad +4 => 2-way bank aliasing only (free on CDNA4).
// ---------------------------------------------------------------------------
template <bool HAS_IDX, bool HAS_ADD>
__global__ __launch_bounds__(256) void gemm_kernel(
    const float* __restrict__ A, int lda,
    const float* __restrict__ B, int ldb, int boff,
    const float* __restrict__ bias,
    const float* __restrict__ addvec, const int* __restrict__ addidx,
    const int* __restrict__ rowidx,
    float* __restrict__ C, int ldc,
    int Mrows, int Ncols, int Kdim)
{
    __shared__ float As[16][68];
    __shared__ float Bs[16][68];
    const int tid = threadIdx.x;
    const int tx = tid & 15;   // col group (4 cols)
    const int ty = tid >> 4;   // row group (4 rows)
    const int rowBase = blockIdx.x * 64;
    const int colBase = blockIdx.y * 64;

    // loader coordinates: one float4 of A and one of B per thread per K-tile
    const int l_r = tid >> 2;         // 0..63 tile row
    const int l_k = (tid & 3) << 2;   // 0,4,8,12

    const int growA = rowBase + l_r;
    const bool aok = growA < Mrows;
    long abase = 0;
    if (aok) {
        const int ar = HAS_IDX ? rowidx[growA] : growA;
        abase = (long)ar * lda;
    }
    const long bbase = (long)(colBase + l_r) * ldb + boff; // Ncols % 64 == 0 always

    float acc[4][4] = {};

    for (int k0 = 0; k0 < Kdim; k0 += 16) {
        const int kk = k0 + l_k;
        float4 av = make_float4(0.f, 0.f, 0.f, 0.f);
        if (aok) {
            const float* ap = A + abase + kk;
            if (kk + 3 < Kdim) {
                av = *reinterpret_cast<const float4*>(ap);
            } else {
                if (kk     < Kdim) av.x = ap[0];
                if (kk + 1 < Kdim) av.y = ap[1];
                if (kk + 2 < Kdim) av.z = ap[2];
                if (kk + 3 < Kdim) av.w = ap[3];
            }
        }
        As[l_k + 0][l_r] = av.x;
        As[l_k + 1][l_r] = av.y;
        As[l_k + 2][l_r] = av.z;
        As[l_k + 3][l_r] = av.w;

        float4 bv = make_float4(0.f, 0.f, 0.f, 0.f);
        {
            const float* bp = B + bbase + kk;
            if (kk + 3 < Kdim) {
                bv = *reinterpret_cast<const float4*>(bp);
            } else {
                if (kk     < Kdim) bv.x = bp[0];
                if (kk + 1 < Kdim) bv.y = bp[1];
                if (kk + 2 < Kdim) bv.z = bp[2];
                if (kk + 3 < Kdim) bv.w = bp[3];
            }
        }
        Bs[l_k + 0][l_r] = bv.x;
        Bs[l_k + 1][l_r] = bv.y;
        Bs[l_k + 2][l_r] = bv.z;
        Bs[l_k + 3][l_r] = bv.w;

        __syncthreads();

        #pragma unroll
        for (int k = 0; k < 16; k++) {
            const float4 ra = *reinterpret_cast<const float4*>(&As[k][ty << 2]);
            const float4 rb = *reinterpret_cast<const float4*>(&Bs[k][tx << 2]);
            const float a_[4] = {ra.x, ra.y, ra.z, ra.w};
            const float b_[4] = {rb.x, rb.y, rb.z, rb.w};
            #pragma unroll
            for (int i = 0; i < 4; i++)
                #pragma unroll
                for (int j = 0; j < 4; j++)
                    acc[i][j] = fmaf(a_[i], b_[j], acc[i][j]);
        }
        __syncthreads();
    }

    const int c0 = colBase + (tx << 2);
    float4 badd = make_float4(0.f, 0.f, 0.f, 0.f);
    if (bias) badd = *reinterpret_cast<const float4*>(&bias[c0]);
    #pragma unroll
    for (int i = 0; i < 4; i++) {
        const int r = rowBase + (ty << 2) + i;
        if (r < Mrows) {
            float4 v;
            v.x = acc[i][0] + badd.x;
            v.y = acc[i][1] + badd.y;
            v.z = acc[i][2] + badd.z;
            v.w = acc[i][3] + badd.w;
            if (HAS_ADD) {
                const int lab = addidx[r];
                const float4 p =
                    *reinterpret_cast<const float4*>(&addvec[(long)lab * OUT2 + c0]);
                v.x += p.x; v.y += p.y; v.z += p.z; v.w += p.w;
            }
            *reinterpret_cast<float4*>(&C[(long)r * ldc + c0]) = v;
        }
    }
}

// Column sums + sumsq over h[rows, 256]. sums[0..255]=sum, sums[256..511]=sumsq.
__global__ __launch_bounds__(256) void bn_stats(
    const float* __restrict__ h, int rows, float* __restrict__ sums)
{
    const int col = threadIdx.x;
    const int per = (rows + gridDim.x - 1) / gridDim.x;
    const int r0 = blockIdx.x * per;
    const int r1 = min(rows, r0 + per);
    float s = 0.f, ss = 0.f;
    for (int r = r0; r < r1; r++) {
        const float v = h[(long)r * H_F + col];
        s += v;
        ss = fmaf(v, v, ss);
    }
    atomicAdd(&sums[col], s);
    atomicAdd(&sums[col + H_F], ss);
}

// Fold mean/var/gamma/beta into per-column scale/shift.
__global__ __launch_bounds__(256) void bn_finalize(
    const float* __restrict__ sums, const float* __restrict__ g,
    const float* __restrict__ beta, float* __restrict__ ss_out)
{
    const int j = threadIdx.x;
    const float invN = 1.0f / (float)N_TOT;
    const float mean = sums[j] * invN;
    const float var  = sums[j + H_F] * invN - mean * mean;
    const float rs = rsqrtf(var + BN_EPS);
    const float sc = rs * g[j];
    ss_out[j] = sc;
    ss_out[j + H_F] = beta[j] - mean * sc;
}

// In-place y = relu(x*scale[col] + shift[col]), float4 vectorized.
__global__ __launch_bounds__(256) void bn_relu(
    float* __restrict__ h, const float* __restrict__ ss, int total4)
{
    const int i = blockIdx.x * blockDim.x + threadIdx.x;
    if (i < total4) {
        float4 v = reinterpret_cast<float4*>(h)[i];
        const int c = (i << 2) & (H_F - 1);
        v.x = fmaxf(0.f, fmaf(v.x, ss[c + 0], ss[c + 256]));
        v.y = fmaxf(0.f, fmaf(v.y, ss[c + 1], ss[c + 257]));
        v.z = fmaxf(0.f, fmaf(v.z, ss[c + 2], ss[c + 258]));
        v.w = fmaxf(0.f, fmaf(v.w, ss[c + 3], ss[c + 259]));
        reinterpret_cast<float4*>(h)[i] = v;
    }
}

// labels[m] = argmax(cluster_id[m,:]) (first max, matches jnp.argmax on one-hot)
__global__ __launch_bounds__(256) void labels_kernel(
    const float* __restrict__ cid, int* __restrict__ labels, int* __restrict__ counts)
{
    const int m = blockIdx.x * blockDim.x + threadIdx.x;
    if (m < M_ROWS) {
        const float* row = cid + (long)m * K_CL;
        int best = 0;
        float bv = row[0];
        for (int k = 1; k < K_CL; k++) {
            const float v = row[k];
            if (v > bv) { bv = v; best = k; }
        }
        labels[m] = best;
        atomicAdd(&counts[best], 1);
    }
}

// Per-block LDS [K,H] accumulator; thread j owns column j (race-free plain adds),
// one global atomic per LDS slot per block at the end.
__global__ __launch_bounds__(256) void seg_sum(
    const float* __restrict__ h2, const int* __restrict__ cidx,
    const int* __restrict__ labels, float* __restrict__ csum)
{
    __shared__ float ls[K_CL * H_F];
    for (int i = threadIdx.x; i < K_CL * H_F; i += blockDim.x) ls[i] = 0.f;
    __syncthreads();
    const int per = (M_ROWS + gridDim.x - 1) / gridDim.x;
    const int m0 = blockIdx.x * per;
    const int m1 = min(M_ROWS, m0 + per);
    const int j = threadIdx.x; // owns column j
    for (int m = m0; m < m1; m++) {
        const int lab = labels[m];
        const int row = cidx[m];
        ls[lab * H_F + j] += h2[(long)row * H_F + j];
    }
    __syncthreads();
    for (int i = threadIdx.x; i < K_CL * H_F; i += blockDim.x) {
        const float v = ls[i];
        if (v != 0.f) atomicAdd(&csum[i], v);
    }
}

__global__ __launch_bounds__(256) void cf_kernel(
    const float* __restrict__ csum, const int* __restrict__ counts,
    float* __restrict__ cf)
{
    const int i = blockIdx.x * blockDim.x + threadIdx.x;
    if (i < K_CL * H_F) {
        const int k = i >> 8; // / H_F
        cf[i] = csum[i] / (float)counts[k];
    }
}

extern "C" void kernel_launch(void* const* d_in, const int* in_sizes, int n_in,
                              void* d_out, int out_size, void* d_ws, size_t ws_size,
                              hipStream_t stream)
{
    const float* x    = (const float*)d_in[0];
    const float* cid  = (const float*)d_in[1];
    const int*   cidx = (const int*)  d_in[2];
    const float* W1   = (const float*)d_in[3];
    const float* b1   = (const float*)d_in[4];
    const float* g1   = (const float*)d_in[5];
    const float* be1  = (const float*)d_in[6];
    const float* W2   = (const float*)d_in[7];
    const float* b2   = (const float*)d_in[8];
    const float* g2   = (const float*)d_in[9];
    const float* be2  = (const float*)d_in[10];
    const float* Wfc  = (const float*)d_in[11];
    const float* bfc  = (const float*)d_in[12];
    float* out = (float*)d_out;

    char* ws = (char*)d_ws;
    size_t off = 0;
    auto alloc = [&](size_t bytes) -> void* {
        void* p = ws + off;
        off += (bytes + 255) & ~(size_t)255;
        return p;
    };
    float* h1    = (float*)alloc((size_t)N_TOT * H_F * 4);
    float* h2    = (float*)alloc((size_t)N_TOT * H_F * 4);
    float* sums1 = (float*)alloc(2 * H_F * 4);
    float* ss1   = (float*)alloc(2 * H_F * 4);
    float* sums2 = (float*)alloc(2 * H_F * 4);
    float* ss2   = (float*)alloc(2 * H_F * 4);
    int*   counts= (int*)  alloc(K_CL * 4);
    int*   labels= (int*)  alloc(M_ROWS * 4);
    float* csum  = (float*)alloc(K_CL * H_F * 4);
    float* cf    = (float*)alloc(K_CL * H_F * 4);
    float* P     = (float*)alloc((size_t)K_CL * OUT2 * 4);
    float* Q     = (float*)alloc((size_t)K_CL * OUT2 * 4);
    (void)ws_size; (void)in_sizes; (void)n_in; (void)out_size;

    // Zero the accumulator span (sums1 .. csum inclusive; ws is poisoned 0xAA).
    {
        char* z0 = (char*)sums1;
        char* z1 = (char*)csum + ((K_CL * H_F * 4 + 255) & ~255);
        hipMemsetAsync(z0, 0, (size_t)(z1 - z0), stream);
    }

    const dim3 blk(256);

    // labels + counts (independent of the GEMM chain)
    labels_kernel<<<dim3((M_ROWS + 255) / 256), blk, 0, stream>>>(cid, labels, counts);

    // layer 1: h1 = relu(bn(x @ W1.T + b1))
    gemm_kernel<false, false><<<dim3((N_TOT + 63) / 64, H_F / 64), blk, 0, stream>>>(
        x, IN_F, W1, IN_F, 0, b1, nullptr, nullptr, nullptr, h1, H_F, N_TOT, H_F, IN_F);
    bn_stats<<<dim3(256), blk, 0, stream>>>(h1, N_TOT, sums1);
    bn_finalize<<<dim3(1), blk, 0, stream>>>(sums1, g1, be1, ss1);
    bn_relu<<<dim3((N_TOT * H_F / 4 + 255) / 256), blk, 0, stream>>>(h1, ss1, N_TOT * H_F / 4);

    // layer 2: h2 = relu(bn(h1 @ W2.T + b2))
    gemm_kernel<false, false><<<dim3((N_TOT + 63) / 64, H_F / 64), blk, 0, stream>>>(
        h1, H_F, W2, H_F, 0, b2, nullptr, nullptr, nullptr, h2, H_F, N_TOT, H_F, H_F);
    bn_stats<<<dim3(256), blk, 0, stream>>>(h2, N_TOT, sums2);
    bn_finalize<<<dim3(1), blk, 0, stream>>>(sums2, g2, be2, ss2);
    bn_relu<<<dim3((N_TOT * H_F / 4 + 255) / 256), blk, 0, stream>>>(h2, ss2, N_TOT * H_F / 4);

    // cluster mean features cf[K,H]
    seg_sum<<<dim3(100), blk, 0, stream>>>(h2, cidx, labels, csum);
    cf_kernel<<<dim3((K_CL * H_F + 255) / 256), blk, 0, stream>>>(csum, counts, cf);

    // P = cf @ WfcB.T ; Q = cf @ WfcA.T   (tiny: 40x1024, K=256)
    gemm_kernel<false, false><<<dim3(1, OUT2 / 64), blk, 0, stream>>>(
        cf, H_F, Wfc, 2 * H_F, H_F, nullptr, nullptr, nullptr, nullptr, P, OUT2, K_CL, OUT2, H_F);
    gemm_kernel<false, false><<<dim3(1, OUT2 / 64), blk, 0, stream>>>(
        cf, H_F, Wfc, 2 * H_F, 0, nullptr, nullptr, nullptr, nullptr, Q, OUT2, K_CL, OUT2, H_F);

    // out[m]     = xc@WfcA.T + P[label[m]] + bfc
    // out[M+m]   = xc@WfcB.T + Q[label[m]] + bfc
    gemm_kernel<true, true><<<dim3((M_ROWS + 63) / 64, OUT2 / 64), blk, 0, stream>>>(
        h2, H_F, Wfc, 2 * H_F, 0, bfc, P, labels, cidx, out, OUT2, M_ROWS, OUT2, H_F);
    gemm_kernel<true, true><<<dim3((M_ROWS + 63) / 64, OUT2 / 64), blk, 0, stream>>>(
        h2, H_F, Wfc, 2 * H_F, H_F, bfc, Q, labels, cidx,
        out + (size_t)M_ROWS * OUT2, OUT2, M_ROWS, OUT2, H_F);
}